// Round 14
// baseline (10781.371 us; speedup 1.0000x reference)
//
#include <hip/hip_runtime.h>
#include <math.h>

#define BATCH 512
#define TLEN  64
#define HD    512
#define H2    1024
#define H3    1536
#define HQ    51
#define CHUNK 4096
#define ARENA_BIT 64
#define MAXRT 1024

typedef __attribute__((ext_vector_type(8))) short bf16x8;
typedef __attribute__((ext_vector_type(16))) float f32x16;

struct Task { int b, el, er, jl, slot; };

struct P {
    const float* inp; const int* length;
    const float* W1; const float* b1; const float* W2; const float* b2;
    const float* Wq1; const float* bq1; const float* Wq2; const float* bq2;
    float* out;
    short *W1a, *W1b, *W1c, *W2a, *W2b, *W2c;
    float* Wq1T;                  // [HD][HQ] transposed Wq1 (coalesced score reads)
    float* Vif;
    short *X2a, *X2b, *X2c;
    float* arena;
    float* comp; int* posval; int* cidx;
    Task* itasks; Task* rtasks;   // rtasks: 64 iteration slots x MAXRT
    int* rti;                     // 64 slots x BATCH*2
    int* rcnt;                    // 64
    int* cnt_init;
};

__device__ __forceinline__ float sigf(float x) { return 1.0f / (1.0f + expf(-x)); }

__device__ __forceinline__ unsigned short f2bf(float f) {
    unsigned u = __builtin_bit_cast(unsigned, f);
    u += 0x7fffu + ((u >> 16) & 1u);
    return (unsigned short)(u >> 16);
}
__device__ __forceinline__ float bf2f(unsigned short h) {
    unsigned u = ((unsigned)h) << 16;
    return __builtin_bit_cast(float, u);
}
__device__ __forceinline__ void split3(float f, short& a, short& b, short& c) {
    unsigned short h1 = f2bf(f);
    float r1 = f - bf2f(h1);
    unsigned short h2 = f2bf(r1);
    float r2 = r1 - bf2f(h2);
    unsigned short h3 = f2bf(r2);
    a = (short)h1; b = (short)h2; c = (short)h3;
}

__device__ __forceinline__ const float* node_ptr(const float* __restrict__ inp,
                                                 const float* __restrict__ arena,
                                                 int b, int enc)
{
    const float* base = (enc & ARENA_BIT) ? arena : inp;
    return base + ((long)b * TLEN + (enc & (ARENA_BIT - 1))) * HD;
}

#define MFMA6(a1,a2,a3,b1,b2,b3,acc) \
    acc = __builtin_amdgcn_mfma_f32_32x32x16_bf16(a1, b1, acc, 0, 0, 0); \
    acc = __builtin_amdgcn_mfma_f32_32x32x16_bf16(a1, b2, acc, 0, 0, 0); \
    acc = __builtin_amdgcn_mfma_f32_32x32x16_bf16(a2, b1, acc, 0, 0, 0); \
    acc = __builtin_amdgcn_mfma_f32_32x32x16_bf16(a1, b3, acc, 0, 0, 0); \
    acc = __builtin_amdgcn_mfma_f32_32x32x16_bf16(a2, b2, acc, 0, 0, 0); \
    acc = __builtin_amdgcn_mfma_f32_32x32x16_bf16(a3, b1, acc, 0, 0, 0);

// fp64 score accumulation from transposed Wq1 — same values/order as row-major version
__device__ __forceinline__ double score_T(const float* __restrict__ wt, const float* __restrict__ nh,
                                          int q, double bias)
{
    double s0 = 0.0, s1 = 0.0, s2 = 0.0, s3 = 0.0;
    for (int k = 0; k < HD; k += 4) {
        s0 += (double)wt[(k + 0) * HQ + q] * (double)nh[k + 0];
        s1 += (double)wt[(k + 1) * HQ + q] * (double)nh[k + 1];
        s2 += (double)wt[(k + 2) * HQ + q] * (double)nh[k + 2];
        s3 += (double)wt[(k + 3) * HQ + q] * (double)nh[k + 3];
    }
    return bias + s0 + s1 + s2 + s3;
}

// ================= prep / init tasks =================

__global__ void k_prep(P A)
{
    long tid = (long)blockIdx.x * blockDim.x + threadIdx.x;
    long nth = (long)gridDim.x * blockDim.x;
    for (long i = tid; i < (long)H3 * H2; i += nth) {
        short a, b, c; split3(A.W1[i], a, b, c);
        A.W1a[i] = a; A.W1b[i] = b; A.W1c[i] = c;
    }
    for (long i = tid; i < (long)HD * H2; i += nth) {
        short a, b, c; split3(A.W2[i], a, b, c);
        A.W2a[i] = a; A.W2b[i] = b; A.W2c[i] = c;
    }
    for (long i = tid; i < (long)HD * HQ; i += nth) {
        long k = i / HQ, q = i - k * HQ;
        A.Wq1T[i] = A.Wq1[q * HD + k];
    }
    for (long i = tid; i < BATCH * TLEN; i += nth) {
        int j = (int)(i % TLEN);
        A.posval[i] = j;
        A.cidx[i] = j;
    }
    for (long i = tid; i < BATCH * 2; i += nth) A.rti[i] = -1;   // iteration slot 0
    for (long i = tid; i < 64; i += nth) A.rcnt[i] = 0;
    if (tid == 0) *A.cnt_init = 0;
}

__global__ void k_init_tasks(const int* __restrict__ length, Task* __restrict__ tasks, int* __restrict__ cnt)
{
    int b = blockIdx.x, j = threadIdx.x;
    int len = length[b];
    if (j < len - 1) {
        int idx = atomicAdd(cnt, 1);
        Task t; t.b = b; t.el = j; t.er = j + 1; t.jl = j; t.slot = j;
        tasks[idx] = t;
    }
}

// ================= G1 (R12 verbatim): LDS-staged split + MFMA, pipelined, conflict-free =================
// LDS layout: sX[seg=ch*2+hi][row 0..63][8 shorts].
__launch_bounds__(256, 6)
__global__ void k_g1(P A, const Task* __restrict__ tasks, const int* __restrict__ cnt, int task_off)
{
    __shared__ const float* pL[64];
    __shared__ const float* pR[64];
    __shared__ int tok[64];
    __shared__ __align__(16) short sXa[4 * 64 * 8];
    __shared__ __align__(16) short sXb[4 * 64 * 8];
    __shared__ __align__(16) short sXc[4 * 64 * 8];
    int count = *cnt;
    int m_base = task_off + (int)blockIdx.x * 64;
    if (m_base >= count) return;
    int tid = threadIdx.x;
    if (tid < 64) {
        int mg = m_base + tid;
        if (mg < count) {
            Task t = tasks[mg];
            pL[tid] = node_ptr(A.inp, A.arena, t.b, t.el);
            pR[tid] = node_ptr(A.inp, A.arena, t.b, t.er);
            tok[tid] = 1;
        } else { pL[tid] = A.inp; pR[tid] = A.inp; tok[tid] = 0; }
    }
    __syncthreads();
    const int n0 = blockIdx.y * 64;
    const int wid = tid >> 6, lane = tid & 63;
    const int wr = wid >> 1, wc = wid & 1;
    const int lrow = lane & 31, lhi = lane >> 5;
    const int colg = n0 + wc * 32 + lrow;
    const long wb = (long)colg * H2;
    const int srow = tid >> 2, smk = (tid & 3) * 8;   // smk/8 = seg = ch*2+hi
    const int wofs = (tid & 3) * 512 + srow * 8;      // write offset (shorts)
    const int rrow = wr * 32 + lrow;                  // fragment A-row

    const float* myL = pL[srow];
    const float* myR = pR[srow];

    f32x16 acc;
    #pragma unroll
    for (int r = 0; r < 16; ++r) acc[r] = 0.0f;

    float4 nv0 = *(const float4*)(myL + smk);
    float4 nv1 = *(const float4*)(myL + smk + 4);

    for (int kt = 0; kt < 32; ++kt) {
        const int k0 = kt * 32;
        float4 v0 = nv0, v1 = nv1;
        if (kt < 31) {
            const int k0n = (kt + 1) * 32;
            const float* nsrc = (k0n < HD ? myL + k0n + smk : myR + k0n - HD + smk);
            nv0 = *(const float4*)nsrc;
            nv1 = *(const float4*)(nsrc + 4);
        }
        {
            float f[8] = {v0.x, v0.y, v0.z, v0.w, v1.x, v1.y, v1.z, v1.w};
            bf16x8 ha, hb, hc;
            #pragma unroll
            for (int j = 0; j < 8; ++j) {
                short s1, s2, s3;
                split3(f[j], s1, s2, s3);
                ha[j] = s1; hb[j] = s2; hc[j] = s3;
            }
            *(bf16x8*)&sXa[wofs] = ha;
            *(bf16x8*)&sXb[wofs] = hb;
            *(bf16x8*)&sXc[wofs] = hc;
        }
        __syncthreads();
        #pragma unroll
        for (int ch = 0; ch < 2; ++ch) {
            const int ko = k0 + ch * 16 + lhi * 8;
            const int ao = (ch * 2 + lhi) * 512 + rrow * 8;
            bf16x8 a1 = *(const bf16x8*)&sXa[ao];
            bf16x8 a2 = *(const bf16x8*)&sXb[ao];
            bf16x8 a3 = *(const bf16x8*)&sXc[ao];
            bf16x8 b1 = *(const bf16x8*)&A.W1a[wb + ko];
            bf16x8 b2 = *(const bf16x8*)&A.W1b[wb + ko];
            bf16x8 b3 = *(const bf16x8*)&A.W1c[wb + ko];
            MFMA6(a1, a2, a3, b1, b2, b3, acc)
        }
        __syncthreads();
    }
    #pragma unroll
    for (int r = 0; r < 16; ++r) {
        int rl = wr * 32 + (r & 3) + 8 * (r >> 2) + 4 * lhi;
        if (!tok[rl]) continue;
        long vrow = (long)blockIdx.x * 64 + rl;
        float v = acc[r] + A.b1[colg];
        if (n0 < H2) {
            A.Vif[vrow * H2 + colg] = v;
        } else {
            int c2 = colg - H2;
            float rs = sigf(v);
            float xl = pL[rl][c2] * rs;
            float xr = pR[rl][c2] * rs;
            short s1, s2, s3;
            split3(xl, s1, s2, s3);
            long o1 = vrow * H2 + c2;
            A.X2a[o1] = s1; A.X2b[o1] = s2; A.X2c[o1] = s3;
            split3(xr, s1, s2, s3);
            long o2 = o1 + HD;
            A.X2a[o2] = s1; A.X2b[o2] = s2; A.X2c[o2] = s3;
        }
    }
}

// ================= G2 (R12 verbatim) =================
__launch_bounds__(256, 6)
__global__ void k_g2(P A, const Task* __restrict__ tasks, const int* __restrict__ cnt, int task_off)
{
    __shared__ const float* pL[64];
    __shared__ const float* pR[64];
    __shared__ int dr[64];
    __shared__ int tok[64];
    int count = *cnt;
    int m_base = task_off + (int)blockIdx.x * 64;
    if (m_base >= count) return;
    int tid = threadIdx.x;
    if (tid < 64) {
        int mg = m_base + tid;
        if (mg < count) {
            Task t = tasks[mg];
            pL[tid] = node_ptr(A.inp, A.arena, t.b, t.el);
            pR[tid] = node_ptr(A.inp, A.arena, t.b, t.er);
            dr[tid] = t.b * TLEN + t.slot;
            tok[tid] = 1;
        } else { pL[tid] = A.inp; pR[tid] = A.inp; dr[tid] = 0; tok[tid] = 0; }
    }
    __syncthreads();
    const int n0 = blockIdx.y * 64;
    const int wid = tid >> 6, lane = tid & 63;
    const int wr = wid >> 1, wc = wid & 1;
    const int lrow = lane & 31, lhi = lane >> 5;
    const int colg = n0 + wc * 32 + lrow;
    const long wb = (long)colg * H2;
    const long arow = (long)((int)blockIdx.x * 64 + wr * 32 + lrow) * H2;
    const int klo = lhi * 8;

    f32x16 acc;
    #pragma unroll
    for (int r = 0; r < 16; ++r) acc[r] = 0.0f;

    #pragma unroll 4
    for (int kt = 0; kt < 32; ++kt) {
        #pragma unroll
        for (int ch = 0; ch < 2; ++ch) {
            const int ko = kt * 32 + ch * 16 + klo;
            bf16x8 a1 = *(const bf16x8*)&A.X2a[arow + ko];
            bf16x8 a2 = *(const bf16x8*)&A.X2b[arow + ko];
            bf16x8 a3 = *(const bf16x8*)&A.X2c[arow + ko];
            bf16x8 b1 = *(const bf16x8*)&A.W2a[wb + ko];
            bf16x8 b2 = *(const bf16x8*)&A.W2b[wb + ko];
            bf16x8 b3 = *(const bf16x8*)&A.W2c[wb + ko];
            MFMA6(a1, a2, a3, b1, b2, b3, acc)
        }
    }
    #pragma unroll
    for (int r = 0; r < 16; ++r) {
        int rl = wr * 32 + (r & 3) + 8 * (r >> 2) + 4 * lhi;
        if (!tok[rl]) continue;
        long vrow = (long)blockIdx.x * 64 + rl;
        float hh = acc[r] + A.b2[colg];
        float vi = A.Vif[vrow * H2 + colg];
        float vf = A.Vif[vrow * H2 + HD + colg];
        float l = pL[rl][colg];
        float rr = pR[rl][colg];
        float nh = (l + rr) * sigf(vf) + tanhf(hh) * sigf(vi);
        A.arena[(long)dr[rl] * HD + colg] = nh;
    }
}

// ================= init scoring (fp64, coalesced Wq1T reads; single launch) =================
__launch_bounds__(64)
__global__ void k_g3(P A)
{
    int tgl = blockIdx.x;
    if (tgl >= *A.cnt_init) return;
    Task t = A.itasks[tgl];
    int tid = threadIdx.x;
    __shared__ float nh[HD];
    __shared__ double part[64];
    const float* src = &A.arena[((long)t.b * TLEN + t.slot) * HD];
    for (int c = tid; c < HD; c += 64) nh[c] = src[c];
    __syncthreads();
    double p = 0.0;
    if (tid < HQ) {
        double a = score_T(A.Wq1T, nh, tid, (double)A.bq1[tid]);
        p = tanh(a) * (double)A.Wq2[tid];
    }
    part[tid] = p;
    __syncthreads();
    if (tid == 0) {
        double s = 0.0;
        for (int r = 0; r < HQ; ++r) s += part[r];
        s += (double)A.bq2[0];
        A.comp[t.b * TLEN + t.jl] = (float)s;
    }
}

// ================= select: 128 threads, wave w scores task w (coalesced Wq1T) =================
__launch_bounds__(128)
__global__ void k_select(P A, int iter, long off_i)
{
    int b = blockIdx.x, tid = threadIdx.x;
    __shared__ float nh[2][HD];
    __shared__ double part[2][64];
    __shared__ int sh[4];
    const Task* rtc = A.rtasks + (long)iter * MAXRT;
    Task* rtn = A.rtasks + (long)(iter + 1) * MAXRT;
    const int* ric = A.rti + (long)iter * (BATCH * 2);
    int* rin = A.rti + (long)(iter + 1) * (BATCH * 2);
    int* rc_nxt = A.rcnt + iter + 1;
    int len = A.length[b];
    if (iter == 62) {
        if (tid == 0 && len == TLEN) A.posval[b * TLEN + 0] = ARENA_BIT | A.cidx[b * TLEN + 0];
        return;
    }
    // 1) refresh comp: wave w handles task w
    {
        int w = tid >> 6, lane = tid & 63;
        int ti = ric[b * 2 + w];
        if (ti >= 0) {
            Task tk = rtc[ti];
            const float* src = &A.arena[((long)b * TLEN + tk.slot) * HD];
            for (int c = lane; c < HD; c += 64) nh[w][c] = src[c];
            double p = 0.0;
            if (lane < HQ) {
                double a = score_T(A.Wq1T, nh[w], lane, (double)A.bq1[lane]);
                p = tanh(a) * (double)A.Wq2[lane];
            }
            part[w][lane] = p;
            if (lane == 0) {
                double s = 0.0;
                for (int r = 0; r < HQ; ++r) s += part[w][r];
                s += (double)A.bq2[0];
                A.comp[b * TLEN + tk.jl] = (float)s;
            }
        }
    }
    __syncthreads();
    // 2) argmax + mask
    int L1 = 63 - iter;
    if (tid == 0) {
        float best = -INFINITY; int bj = 0;
        for (int j = 0; j < L1; ++j) {
            float v = (iter + 1 + j < len) ? A.comp[b * TLEN + j] : -3.402823466e38f;
            if (v > best) { best = v; bj = j; }
        }
        sh[0] = bj;
    }
    __syncthreads();
    int bj = sh[0];
    if (tid < L1) A.out[off_i + (long)b * L1 + tid] = (tid == bj) ? 1.0f : 0.0f;
    bool active = (iter + 1) < len;
    if (active) {
        int vcnt = len - iter - 2;
        if (tid == 0) {
            sh[1] = A.cidx[b * TLEN + bj];
            sh[2] = (bj < vcnt) ? A.cidx[b * TLEN + bj + 1] : -1;
        }
        __syncthreads();
        int sM = sh[1], sOld = sh[2];
        int newL = 63 - iter;
        int pv = 0;  bool dp = (tid >= bj + 1 && tid <= newL - 1);
        if (dp) pv = A.posval[b * TLEN + tid + 1];
        float cv = 0; int civ = 0; bool dc = (tid >= bj + 1 && tid <= newL - 2);
        if (dc) { cv = A.comp[b * TLEN + tid + 1]; civ = A.cidx[b * TLEN + tid + 1]; }
        __syncthreads();
        if (dp) A.posval[b * TLEN + tid] = pv;
        if (dc) { A.comp[b * TLEN + tid] = cv; A.cidx[b * TLEN + tid] = civ; }
        if (tid == 0) A.posval[b * TLEN + bj] = ARENA_BIT | sM;
        __syncthreads();
        if (tid == 0) {
            for (int t = 0; t < 2; ++t) {
                int jn = bj - 1 + t;
                int r = -1;
                if (jn >= 0 && jn < vcnt) {
                    int slot = (t == 0) ? A.cidx[b * TLEN + jn] : sOld;
                    A.cidx[b * TLEN + jn] = slot;
                    r = atomicAdd(rc_nxt, 1);
                    Task tk; tk.b = b;
                    tk.el = A.posval[b * TLEN + jn];
                    tk.er = A.posval[b * TLEN + jn + 1];
                    tk.jl = jn; tk.slot = slot;
                    rtn[r] = tk;
                }
                rin[b * 2 + t] = r;
            }
        }
    } else {
        if (tid == 0) { rin[b * 2] = -1; rin[b * 2 + 1] = -1; }
    }
}

// ================= final output =================
__global__ void k_out(P A)
{
    int i = blockIdx.x * blockDim.x + threadIdx.x;
    if (i < BATCH * HD) {
        int b = i / HD, c = i % HD;
        const float* src = node_ptr(A.inp, A.arena, b, A.posval[b * TLEN + 0]);
        A.out[i] = src[c];
    }
}

// ================= launch =================
extern "C" void kernel_launch(void* const* d_in, const int* in_sizes, int n_in,
                              void* d_out, int out_size, void* d_ws, size_t ws_size,
                              hipStream_t stream)
{
    P a;
    a.inp = (const float*)d_in[0];
    a.length = (const int*)d_in[1];
    a.W1 = (const float*)d_in[2];
    a.b1 = (const float*)d_in[3];
    a.W2 = (const float*)d_in[4];
    a.b2 = (const float*)d_in[5];
    a.Wq1 = (const float*)d_in[6];
    a.bq1 = (const float*)d_in[7];
    a.Wq2 = (const float*)d_in[8];
    a.bq2 = (const float*)d_in[9];
    a.out = (float*)d_out;

    char* p = (char*)d_ws;
    auto alloc = [&](size_t bytes) { char* r = p; p += (bytes + 255) & ~(size_t)255; return r; };
    a.W1a = (short*)alloc((size_t)H3 * H2 * 2);
    a.W1b = (short*)alloc((size_t)H3 * H2 * 2);
    a.W1c = (short*)alloc((size_t)H3 * H2 * 2);
    a.W2a = (short*)alloc((size_t)HD * H2 * 2);
    a.W2b = (short*)alloc((size_t)HD * H2 * 2);
    a.W2c = (short*)alloc((size_t)HD * H2 * 2);
    a.Wq1T = (float*)alloc((size_t)HD * HQ * 4);
    a.Vif = (float*)alloc((size_t)CHUNK * H2 * 4);
    a.X2a = (short*)alloc((size_t)CHUNK * H2 * 2);
    a.X2b = (short*)alloc((size_t)CHUNK * H2 * 2);
    a.X2c = (short*)alloc((size_t)CHUNK * H2 * 2);
    a.arena = (float*)alloc((size_t)BATCH * TLEN * HD * 4);
    a.comp = (float*)alloc((size_t)BATCH * TLEN * 4);
    a.posval = (int*)alloc((size_t)BATCH * TLEN * 4);
    a.cidx = (int*)alloc((size_t)BATCH * TLEN * 4);
    a.itasks = (Task*)alloc((size_t)BATCH * (TLEN - 1) * sizeof(Task));
    a.rtasks = (Task*)alloc((size_t)64 * MAXRT * sizeof(Task));
    a.rti = (int*)alloc((size_t)64 * BATCH * 2 * 4);
    a.rcnt = (int*)alloc(64 * 4);
    a.cnt_init = (int*)alloc(256);

    k_prep<<<2048, 256, 0, stream>>>(a);
    k_init_tasks<<<BATCH, 64, 0, stream>>>(a.length, a.itasks, a.cnt_init);
    for (int c = 0; c < 8; ++c) {
        int off = c * CHUNK;
        k_g1<<<dim3(CHUNK / 64, 24), 256, 0, stream>>>(a, a.itasks, a.cnt_init, off);
        k_g2<<<dim3(CHUNK / 64, 8), 256, 0, stream>>>(a, a.itasks, a.cnt_init, off);
    }
    k_g3<<<BATCH * (TLEN - 1), 64, 0, stream>>>(a);
    long offi = (long)BATCH * HD;
    for (int i = 0; i < 63; ++i) {
        if (i >= 1) {
            const Task* rt = a.rtasks + (long)i * MAXRT;
            const int* rc = a.rcnt + i;
            k_g1<<<dim3(MAXRT / 64, 24), 256, 0, stream>>>(a, rt, rc, 0);
            k_g2<<<dim3(MAXRT / 64, 8), 256, 0, stream>>>(a, rt, rc, 0);
        }
        k_select<<<BATCH, 128, 0, stream>>>(a, i, offi);
        if (i < 62) offi += (long)BATCH * (63 - i);
    }
    k_out<<<(BATCH * HD + 255) / 256, 256, 0, stream>>>(a);
}

// Round 15
// 10428.893 us; speedup vs baseline: 1.0338x; 1.0338x over previous
//
#include <hip/hip_runtime.h>
#include <math.h>

#define BATCH 512
#define TLEN  64
#define HD    512
#define H2    1024
#define H3    1536
#define HQ    51
#define CHUNK 4096
#define ARENA_BIT 64
#define MAXRT 1024

typedef __attribute__((ext_vector_type(8))) short bf16x8;
typedef __attribute__((ext_vector_type(16))) float f32x16;

struct Task { int b, el, er, jl, slot; };

struct P {
    const float* inp; const int* length;
    const float* W1; const float* b1; const float* W2; const float* b2;
    const float* Wq1; const float* bq1; const float* Wq2; const float* bq2;
    float* out;
    short *W1a, *W1b, *W1c, *W2a, *W2b, *W2c;
    float* Vif;
    short *X2a, *X2b, *X2c;
    float* arena;
    float* comp; int* posval; int* cidx;
    Task* itasks; Task* rtasks;   // rtasks: 64 iteration slots x MAXRT
    int* rti;                     // 64 slots x BATCH*2
    int* rcnt;                    // 64
    int* cnt_init;
};

__device__ __forceinline__ float sigf(float x) { return 1.0f / (1.0f + expf(-x)); }

__device__ __forceinline__ unsigned short f2bf(float f) {
    unsigned u = __builtin_bit_cast(unsigned, f);
    u += 0x7fffu + ((u >> 16) & 1u);
    return (unsigned short)(u >> 16);
}
__device__ __forceinline__ float bf2f(unsigned short h) {
    unsigned u = ((unsigned)h) << 16;
    return __builtin_bit_cast(float, u);
}
__device__ __forceinline__ void split3(float f, short& a, short& b, short& c) {
    unsigned short h1 = f2bf(f);
    float r1 = f - bf2f(h1);
    unsigned short h2 = f2bf(r1);
    float r2 = r1 - bf2f(h2);
    unsigned short h3 = f2bf(r2);
    a = (short)h1; b = (short)h2; c = (short)h3;
}

__device__ __forceinline__ const float* node_ptr(const float* __restrict__ inp,
                                                 const float* __restrict__ arena,
                                                 int b, int enc)
{
    const float* base = (enc & ARENA_BIT) ? arena : inp;
    return base + ((long)b * TLEN + (enc & (ARENA_BIT - 1))) * HD;
}

#define MFMA6(a1,a2,a3,b1,b2,b3,acc) \
    acc = __builtin_amdgcn_mfma_f32_32x32x16_bf16(a1, b1, acc, 0, 0, 0); \
    acc = __builtin_amdgcn_mfma_f32_32x32x16_bf16(a1, b2, acc, 0, 0, 0); \
    acc = __builtin_amdgcn_mfma_f32_32x32x16_bf16(a2, b1, acc, 0, 0, 0); \
    acc = __builtin_amdgcn_mfma_f32_32x32x16_bf16(a1, b3, acc, 0, 0, 0); \
    acc = __builtin_amdgcn_mfma_f32_32x32x16_bf16(a2, b2, acc, 0, 0, 0); \
    acc = __builtin_amdgcn_mfma_f32_32x32x16_bf16(a3, b1, acc, 0, 0, 0);

// ================= prep / init tasks =================

__global__ void k_prep(P A)
{
    long tid = (long)blockIdx.x * blockDim.x + threadIdx.x;
    long nth = (long)gridDim.x * blockDim.x;
    for (long i = tid; i < (long)H3 * H2; i += nth) {
        short a, b, c; split3(A.W1[i], a, b, c);
        A.W1a[i] = a; A.W1b[i] = b; A.W1c[i] = c;
    }
    for (long i = tid; i < (long)HD * H2; i += nth) {
        short a, b, c; split3(A.W2[i], a, b, c);
        A.W2a[i] = a; A.W2b[i] = b; A.W2c[i] = c;
    }
    for (long i = tid; i < BATCH * TLEN; i += nth) {
        int j = (int)(i % TLEN);
        A.posval[i] = j;
        A.cidx[i] = j;
    }
    for (long i = tid; i < BATCH * 2; i += nth) A.rti[i] = -1;   // iteration slot 0
    for (long i = tid; i < 64; i += nth) A.rcnt[i] = 0;
    if (tid == 0) *A.cnt_init = 0;
}

__global__ void k_init_tasks(const int* __restrict__ length, Task* __restrict__ tasks, int* __restrict__ cnt)
{
    int b = blockIdx.x, j = threadIdx.x;
    int len = length[b];
    if (j < len - 1) {
        int idx = atomicAdd(cnt, 1);
        Task t; t.b = b; t.el = j; t.er = j + 1; t.jl = j; t.slot = j;
        tasks[idx] = t;
    }
}

// ================= G1: LDS-staged split + MFMA, pipelined (R12 verbatim) =================
// LDS layout: sX[seg=ch*2+hi][row 0..63][8 shorts].
__launch_bounds__(256, 6)
__global__ void k_g1(P A, const Task* __restrict__ tasks, const int* __restrict__ cnt, int task_off)
{
    __shared__ const float* pL[64];
    __shared__ const float* pR[64];
    __shared__ int tok[64];
    __shared__ __align__(16) short sXa[4 * 64 * 8];
    __shared__ __align__(16) short sXb[4 * 64 * 8];
    __shared__ __align__(16) short sXc[4 * 64 * 8];
    int count = *cnt;
    int m_base = task_off + (int)blockIdx.x * 64;
    if (m_base >= count) return;
    int tid = threadIdx.x;
    if (tid < 64) {
        int mg = m_base + tid;
        if (mg < count) {
            Task t = tasks[mg];
            pL[tid] = node_ptr(A.inp, A.arena, t.b, t.el);
            pR[tid] = node_ptr(A.inp, A.arena, t.b, t.er);
            tok[tid] = 1;
        } else { pL[tid] = A.inp; pR[tid] = A.inp; tok[tid] = 0; }
    }
    __syncthreads();
    const int n0 = blockIdx.y * 64;
    const int wid = tid >> 6, lane = tid & 63;
    const int wr = wid >> 1, wc = wid & 1;
    const int lrow = lane & 31, lhi = lane >> 5;
    const int colg = n0 + wc * 32 + lrow;
    const long wb = (long)colg * H2;
    const int srow = tid >> 2, smk = (tid & 3) * 8;   // smk/8 = seg = ch*2+hi
    const int wofs = (tid & 3) * 512 + srow * 8;      // write offset (shorts)
    const int rrow = wr * 32 + lrow;                  // fragment A-row

    const float* myL = pL[srow];
    const float* myR = pR[srow];

    f32x16 acc;
    #pragma unroll
    for (int r = 0; r < 16; ++r) acc[r] = 0.0f;

    float4 nv0 = *(const float4*)(myL + smk);
    float4 nv1 = *(const float4*)(myL + smk + 4);

    for (int kt = 0; kt < 32; ++kt) {
        const int k0 = kt * 32;
        float4 v0 = nv0, v1 = nv1;
        if (kt < 31) {
            const int k0n = (kt + 1) * 32;
            const float* nsrc = (k0n < HD ? myL + k0n + smk : myR + k0n - HD + smk);
            nv0 = *(const float4*)nsrc;
            nv1 = *(const float4*)(nsrc + 4);
        }
        {
            float f[8] = {v0.x, v0.y, v0.z, v0.w, v1.x, v1.y, v1.z, v1.w};
            bf16x8 ha, hb, hc;
            #pragma unroll
            for (int j = 0; j < 8; ++j) {
                short s1, s2, s3;
                split3(f[j], s1, s2, s3);
                ha[j] = s1; hb[j] = s2; hc[j] = s3;
            }
            *(bf16x8*)&sXa[wofs] = ha;
            *(bf16x8*)&sXb[wofs] = hb;
            *(bf16x8*)&sXc[wofs] = hc;
        }
        __syncthreads();
        #pragma unroll
        for (int ch = 0; ch < 2; ++ch) {
            const int ko = k0 + ch * 16 + lhi * 8;
            const int ao = (ch * 2 + lhi) * 512 + rrow * 8;
            bf16x8 a1 = *(const bf16x8*)&sXa[ao];
            bf16x8 a2 = *(const bf16x8*)&sXb[ao];
            bf16x8 a3 = *(const bf16x8*)&sXc[ao];
            bf16x8 b1 = *(const bf16x8*)&A.W1a[wb + ko];
            bf16x8 b2 = *(const bf16x8*)&A.W1b[wb + ko];
            bf16x8 b3 = *(const bf16x8*)&A.W1c[wb + ko];
            MFMA6(a1, a2, a3, b1, b2, b3, acc)
        }
        __syncthreads();
    }
    #pragma unroll
    for (int r = 0; r < 16; ++r) {
        int rl = wr * 32 + (r & 3) + 8 * (r >> 2) + 4 * lhi;
        if (!tok[rl]) continue;
        long vrow = (long)blockIdx.x * 64 + rl;
        float v = acc[r] + A.b1[colg];
        if (n0 < H2) {
            A.Vif[vrow * H2 + colg] = v;
        } else {
            int c2 = colg - H2;
            float rs = sigf(v);
            float xl = pL[rl][c2] * rs;
            float xr = pR[rl][c2] * rs;
            short s1, s2, s3;
            split3(xl, s1, s2, s3);
            long o1 = vrow * H2 + c2;
            A.X2a[o1] = s1; A.X2b[o1] = s2; A.X2c[o1] = s3;
            split3(xr, s1, s2, s3);
            long o2 = o1 + HD;
            A.X2a[o2] = s1; A.X2b[o2] = s2; A.X2c[o2] = s3;
        }
    }
}

// ================= G2 (R12 verbatim) =================
__launch_bounds__(256, 6)
__global__ void k_g2(P A, const Task* __restrict__ tasks, const int* __restrict__ cnt, int task_off)
{
    __shared__ const float* pL[64];
    __shared__ const float* pR[64];
    __shared__ int dr[64];
    __shared__ int tok[64];
    int count = *cnt;
    int m_base = task_off + (int)blockIdx.x * 64;
    if (m_base >= count) return;
    int tid = threadIdx.x;
    if (tid < 64) {
        int mg = m_base + tid;
        if (mg < count) {
            Task t = tasks[mg];
            pL[tid] = node_ptr(A.inp, A.arena, t.b, t.el);
            pR[tid] = node_ptr(A.inp, A.arena, t.b, t.er);
            dr[tid] = t.b * TLEN + t.slot;
            tok[tid] = 1;
        } else { pL[tid] = A.inp; pR[tid] = A.inp; dr[tid] = 0; tok[tid] = 0; }
    }
    __syncthreads();
    const int n0 = blockIdx.y * 64;
    const int wid = tid >> 6, lane = tid & 63;
    const int wr = wid >> 1, wc = wid & 1;
    const int lrow = lane & 31, lhi = lane >> 5;
    const int colg = n0 + wc * 32 + lrow;
    const long wb = (long)colg * H2;
    const long arow = (long)((int)blockIdx.x * 64 + wr * 32 + lrow) * H2;
    const int klo = lhi * 8;

    f32x16 acc;
    #pragma unroll
    for (int r = 0; r < 16; ++r) acc[r] = 0.0f;

    #pragma unroll 4
    for (int kt = 0; kt < 32; ++kt) {
        #pragma unroll
        for (int ch = 0; ch < 2; ++ch) {
            const int ko = kt * 32 + ch * 16 + klo;
            bf16x8 a1 = *(const bf16x8*)&A.X2a[arow + ko];
            bf16x8 a2 = *(const bf16x8*)&A.X2b[arow + ko];
            bf16x8 a3 = *(const bf16x8*)&A.X2c[arow + ko];
            bf16x8 b1 = *(const bf16x8*)&A.W2a[wb + ko];
            bf16x8 b2 = *(const bf16x8*)&A.W2b[wb + ko];
            bf16x8 b3 = *(const bf16x8*)&A.W2c[wb + ko];
            MFMA6(a1, a2, a3, b1, b2, b3, acc)
        }
    }
    #pragma unroll
    for (int r = 0; r < 16; ++r) {
        int rl = wr * 32 + (r & 3) + 8 * (r >> 2) + 4 * lhi;
        if (!tok[rl]) continue;
        long vrow = (long)blockIdx.x * 64 + rl;
        float hh = acc[r] + A.b2[colg];
        float vi = A.Vif[vrow * H2 + colg];
        float vf = A.Vif[vrow * H2 + HD + colg];
        float l = pL[rl][colg];
        float rr = pR[rl][colg];
        float nh = (l + rr) * sigf(vf) + tanhf(hh) * sigf(vi);
        A.arena[(long)dr[rl] * HD + colg] = nh;
    }
}

// ================= init scoring (fp64, row-major Wq1, single launch; R12 verbatim) =================
__launch_bounds__(64)
__global__ void k_g3(P A)
{
    int tgl = blockIdx.x;
    if (tgl >= *A.cnt_init) return;
    Task t = A.itasks[tgl];
    int tid = threadIdx.x;
    __shared__ float nh[HD];
    __shared__ double part[64];
    const float* src = &A.arena[((long)t.b * TLEN + t.slot) * HD];
    for (int c = tid; c < HD; c += 64) nh[c] = src[c];
    __syncthreads();
    double p = 0.0;
    if (tid < HQ) {
        const float* wr = &A.Wq1[(long)tid * HD];
        double s0 = 0.0, s1 = 0.0, s2 = 0.0, s3 = 0.0;
        for (int k = 0; k < HD; k += 4) {
            s0 += (double)wr[k + 0] * (double)nh[k + 0];
            s1 += (double)wr[k + 1] * (double)nh[k + 1];
            s2 += (double)wr[k + 2] * (double)nh[k + 2];
            s3 += (double)wr[k + 3] * (double)nh[k + 3];
        }
        double a = (double)A.bq1[tid] + s0 + s1 + s2 + s3;
        p = tanh(a) * (double)A.Wq2[tid];
    }
    part[tid] = p;
    __syncthreads();
    if (tid == 0) {
        double s = 0.0;
        for (int r = 0; r < HQ; ++r) s += part[r];
        s += (double)A.bq2[0];
        A.comp[t.b * TLEN + t.jl] = (float)s;
    }
}

// ================= select: 128 threads, wave w scores task w (row-major Wq1; R12 verbatim) =================
__launch_bounds__(128)
__global__ void k_select(P A, int iter, long off_i)
{
    int b = blockIdx.x, tid = threadIdx.x;
    __shared__ float nh[2][HD];
    __shared__ double part[2][64];
    __shared__ int sh[4];
    const Task* rtc = A.rtasks + (long)iter * MAXRT;
    Task* rtn = A.rtasks + (long)(iter + 1) * MAXRT;
    const int* ric = A.rti + (long)iter * (BATCH * 2);
    int* rin = A.rti + (long)(iter + 1) * (BATCH * 2);
    int* rc_nxt = A.rcnt + iter + 1;
    int len = A.length[b];
    if (iter == 62) {
        if (tid == 0 && len == TLEN) A.posval[b * TLEN + 0] = ARENA_BIT | A.cidx[b * TLEN + 0];
        return;
    }
    // 1) refresh comp: wave w handles task w (identical per-task arithmetic to R4)
    {
        int w = tid >> 6, lane = tid & 63;
        int ti = ric[b * 2 + w];
        if (ti >= 0) {
            Task tk = rtc[ti];
            const float* src = &A.arena[((long)b * TLEN + tk.slot) * HD];
            for (int c = lane; c < HD; c += 64) nh[w][c] = src[c];
            double p = 0.0;
            if (lane < HQ) {
                const float* wr = &A.Wq1[(long)lane * HD];
                double s0 = 0.0, s1 = 0.0, s2 = 0.0, s3 = 0.0;
                for (int k = 0; k < HD; k += 4) {
                    s0 += (double)wr[k + 0] * (double)nh[w][k + 0];
                    s1 += (double)wr[k + 1] * (double)nh[w][k + 1];
                    s2 += (double)wr[k + 2] * (double)nh[w][k + 2];
                    s3 += (double)wr[k + 3] * (double)nh[w][k + 3];
                }
                double a = (double)A.bq1[lane] + s0 + s1 + s2 + s3;
                p = tanh(a) * (double)A.Wq2[lane];
            }
            part[w][lane] = p;
            if (lane == 0) {
                double s = 0.0;
                for (int r = 0; r < HQ; ++r) s += part[w][r];
                s += (double)A.bq2[0];
                A.comp[b * TLEN + tk.jl] = (float)s;
            }
        }
    }
    __syncthreads();
    // 2) argmax + mask
    int L1 = 63 - iter;
    if (tid == 0) {
        float best = -INFINITY; int bj = 0;
        for (int j = 0; j < L1; ++j) {
            float v = (iter + 1 + j < len) ? A.comp[b * TLEN + j] : -3.402823466e38f;
            if (v > best) { best = v; bj = j; }
        }
        sh[0] = bj;
    }
    __syncthreads();
    int bj = sh[0];
    if (tid < L1) A.out[off_i + (long)b * L1 + tid] = (tid == bj) ? 1.0f : 0.0f;
    bool active = (iter + 1) < len;
    if (active) {
        int vcnt = len - iter - 2;
        if (tid == 0) {
            sh[1] = A.cidx[b * TLEN + bj];
            sh[2] = (bj < vcnt) ? A.cidx[b * TLEN + bj + 1] : -1;
        }
        __syncthreads();
        int sM = sh[1], sOld = sh[2];
        int newL = 63 - iter;
        int pv = 0;  bool dp = (tid >= bj + 1 && tid <= newL - 1);
        if (dp) pv = A.posval[b * TLEN + tid + 1];
        float cv = 0; int civ = 0; bool dc = (tid >= bj + 1 && tid <= newL - 2);
        if (dc) { cv = A.comp[b * TLEN + tid + 1]; civ = A.cidx[b * TLEN + tid + 1]; }
        __syncthreads();
        if (dp) A.posval[b * TLEN + tid] = pv;
        if (dc) { A.comp[b * TLEN + tid] = cv; A.cidx[b * TLEN + tid] = civ; }
        if (tid == 0) A.posval[b * TLEN + bj] = ARENA_BIT | sM;
        __syncthreads();
        if (tid == 0) {
            for (int t = 0; t < 2; ++t) {
                int jn = bj - 1 + t;
                int r = -1;
                if (jn >= 0 && jn < vcnt) {
                    int slot = (t == 0) ? A.cidx[b * TLEN + jn] : sOld;
                    A.cidx[b * TLEN + jn] = slot;
                    r = atomicAdd(rc_nxt, 1);
                    Task tk; tk.b = b;
                    tk.el = A.posval[b * TLEN + jn];
                    tk.er = A.posval[b * TLEN + jn + 1];
                    tk.jl = jn; tk.slot = slot;
                    rtn[r] = tk;
                }
                rin[b * 2 + t] = r;
            }
        }
    } else {
        if (tid == 0) { rin[b * 2] = -1; rin[b * 2 + 1] = -1; }
    }
}

// ================= final output =================
__global__ void k_out(P A)
{
    int i = blockIdx.x * blockDim.x + threadIdx.x;
    if (i < BATCH * HD) {
        int b = i / HD, c = i % HD;
        const float* src = node_ptr(A.inp, A.arena, b, A.posval[b * TLEN + 0]);
        A.out[i] = src[c];
    }
}

// ================= launch =================
extern "C" void kernel_launch(void* const* d_in, const int* in_sizes, int n_in,
                              void* d_out, int out_size, void* d_ws, size_t ws_size,
                              hipStream_t stream)
{
    P a;
    a.inp = (const float*)d_in[0];
    a.length = (const int*)d_in[1];
    a.W1 = (const float*)d_in[2];
    a.b1 = (const float*)d_in[3];
    a.W2 = (const float*)d_in[4];
    a.b2 = (const float*)d_in[5];
    a.Wq1 = (const float*)d_in[6];
    a.bq1 = (const float*)d_in[7];
    a.Wq2 = (const float*)d_in[8];
    a.bq2 = (const float*)d_in[9];
    a.out = (float*)d_out;

    char* p = (char*)d_ws;
    auto alloc = [&](size_t bytes) { char* r = p; p += (bytes + 255) & ~(size_t)255; return r; };
    a.W1a = (short*)alloc((size_t)H3 * H2 * 2);
    a.W1b = (short*)alloc((size_t)H3 * H2 * 2);
    a.W1c = (short*)alloc((size_t)H3 * H2 * 2);
    a.W2a = (short*)alloc((size_t)HD * H2 * 2);
    a.W2b = (short*)alloc((size_t)HD * H2 * 2);
    a.W2c = (short*)alloc((size_t)HD * H2 * 2);
    a.Vif = (float*)alloc((size_t)CHUNK * H2 * 4);
    a.X2a = (short*)alloc((size_t)CHUNK * H2 * 2);
    a.X2b = (short*)alloc((size_t)CHUNK * H2 * 2);
    a.X2c = (short*)alloc((size_t)CHUNK * H2 * 2);
    a.arena = (float*)alloc((size_t)BATCH * TLEN * HD * 4);
    a.comp = (float*)alloc((size_t)BATCH * TLEN * 4);
    a.posval = (int*)alloc((size_t)BATCH * TLEN * 4);
    a.cidx = (int*)alloc((size_t)BATCH * TLEN * 4);
    a.itasks = (Task*)alloc((size_t)BATCH * (TLEN - 1) * sizeof(Task));
    a.rtasks = (Task*)alloc((size_t)64 * MAXRT * sizeof(Task));
    a.rti = (int*)alloc((size_t)64 * BATCH * 2 * 4);
    a.rcnt = (int*)alloc(64 * 4);
    a.cnt_init = (int*)alloc(256);

    k_prep<<<2048, 256, 0, stream>>>(a);
    k_init_tasks<<<BATCH, 64, 0, stream>>>(a.length, a.itasks, a.cnt_init);
    for (int c = 0; c < 8; ++c) {
        int off = c * CHUNK;
        k_g1<<<dim3(CHUNK / 64, 24), 256, 0, stream>>>(a, a.itasks, a.cnt_init, off);
        k_g2<<<dim3(CHUNK / 64, 8), 256, 0, stream>>>(a, a.itasks, a.cnt_init, off);
    }
    k_g3<<<BATCH * (TLEN - 1), 64, 0, stream>>>(a);
    long offi = (long)BATCH * HD;
    for (int i = 0; i < 63; ++i) {
        if (i >= 1) {
            const Task* rt = a.rtasks + (long)i * MAXRT;
            const int* rc = a.rcnt + i;
            k_g1<<<dim3(MAXRT / 64, 24), 256, 0, stream>>>(a, rt, rc, 0);
            k_g2<<<dim3(MAXRT / 64, 8), 256, 0, stream>>>(a, rt, rc, 0);
        }
        k_select<<<BATCH, 128, 0, stream>>>(a, i, offi);
        if (i < 62) offi += (long)BATCH * (63 - i);
    }
    k_out<<<(BATCH * HD + 255) / 256, 256, 0, stream>>>(a);
}

// Round 16
// 10337.332 us; speedup vs baseline: 1.0430x; 1.0089x over previous
//
#include <hip/hip_runtime.h>
#include <math.h>

#define BATCH 512
#define TLEN  64
#define HD    512
#define H2    1024
#define H3    1536
#define HQ    51
#define CHUNK 4096
#define ARENA_BIT 64
#define MAXRT 1024

typedef __attribute__((ext_vector_type(8))) short bf16x8;
typedef __attribute__((ext_vector_type(16))) float f32x16;

struct Task { int b, el, er, jl, slot; };

struct P {
    const float* inp; const int* length;
    const float* W1; const float* b1; const float* W2; const float* b2;
    const float* Wq1; const float* bq1; const float* Wq2; const float* bq2;
    float* out;
    short *W1a, *W1b, *W1c, *W2a, *W2b, *W2c;
    float* Wq1T;                  // [HD][HQ] transposed Wq1 — used ONLY by k_g3
    float* Vif;
    short *X2a, *X2b, *X2c;
    float* arena;
    float* comp; int* posval; int* cidx;
    Task* itasks; Task* rtasks;   // rtasks: 64 iteration slots x MAXRT
    int* rti;                     // 64 slots x BATCH*2
    int* rcnt;                    // 64
    int* cnt_init;
};

__device__ __forceinline__ float sigf(float x) { return 1.0f / (1.0f + expf(-x)); }

__device__ __forceinline__ unsigned short f2bf(float f) {
    unsigned u = __builtin_bit_cast(unsigned, f);
    u += 0x7fffu + ((u >> 16) & 1u);
    return (unsigned short)(u >> 16);
}
__device__ __forceinline__ float bf2f(unsigned short h) {
    unsigned u = ((unsigned)h) << 16;
    return __builtin_bit_cast(float, u);
}
__device__ __forceinline__ void split3(float f, short& a, short& b, short& c) {
    unsigned short h1 = f2bf(f);
    float r1 = f - bf2f(h1);
    unsigned short h2 = f2bf(r1);
    float r2 = r1 - bf2f(h2);
    unsigned short h3 = f2bf(r2);
    a = (short)h1; b = (short)h2; c = (short)h3;
}

__device__ __forceinline__ const float* node_ptr(const float* __restrict__ inp,
                                                 const float* __restrict__ arena,
                                                 int b, int enc)
{
    const float* base = (enc & ARENA_BIT) ? arena : inp;
    return base + ((long)b * TLEN + (enc & (ARENA_BIT - 1))) * HD;
}

#define MFMA6(a1,a2,a3,b1,b2,b3,acc) \
    acc = __builtin_amdgcn_mfma_f32_32x32x16_bf16(a1, b1, acc, 0, 0, 0); \
    acc = __builtin_amdgcn_mfma_f32_32x32x16_bf16(a1, b2, acc, 0, 0, 0); \
    acc = __builtin_amdgcn_mfma_f32_32x32x16_bf16(a2, b1, acc, 0, 0, 0); \
    acc = __builtin_amdgcn_mfma_f32_32x32x16_bf16(a1, b3, acc, 0, 0, 0); \
    acc = __builtin_amdgcn_mfma_f32_32x32x16_bf16(a2, b2, acc, 0, 0, 0); \
    acc = __builtin_amdgcn_mfma_f32_32x32x16_bf16(a3, b1, acc, 0, 0, 0);

// ================= prep / init tasks =================

__global__ void k_prep(P A)
{
    long tid = (long)blockIdx.x * blockDim.x + threadIdx.x;
    long nth = (long)gridDim.x * blockDim.x;
    for (long i = tid; i < (long)H3 * H2; i += nth) {
        short a, b, c; split3(A.W1[i], a, b, c);
        A.W1a[i] = a; A.W1b[i] = b; A.W1c[i] = c;
    }
    for (long i = tid; i < (long)HD * H2; i += nth) {
        short a, b, c; split3(A.W2[i], a, b, c);
        A.W2a[i] = a; A.W2b[i] = b; A.W2c[i] = c;
    }
    for (long i = tid; i < (long)HD * HQ; i += nth) {
        long k = i / HQ, q = i - k * HQ;
        A.Wq1T[i] = A.Wq1[q * HD + k];
    }
    for (long i = tid; i < BATCH * TLEN; i += nth) {
        int j = (int)(i % TLEN);
        A.posval[i] = j;
        A.cidx[i] = j;
    }
    for (long i = tid; i < BATCH * 2; i += nth) A.rti[i] = -1;   // iteration slot 0
    for (long i = tid; i < 64; i += nth) A.rcnt[i] = 0;
    if (tid == 0) *A.cnt_init = 0;
}

__global__ void k_init_tasks(const int* __restrict__ length, Task* __restrict__ tasks, int* __restrict__ cnt)
{
    int b = blockIdx.x, j = threadIdx.x;
    int len = length[b];
    if (j < len - 1) {
        int idx = atomicAdd(cnt, 1);
        Task t; t.b = b; t.el = j; t.er = j + 1; t.jl = j; t.slot = j;
        tasks[idx] = t;
    }
}

// ================= G1: LDS-staged split + MFMA, pipelined (R12/R15 verbatim) =================
__launch_bounds__(256, 6)
__global__ void k_g1(P A, const Task* __restrict__ tasks, const int* __restrict__ cnt, int task_off)
{
    __shared__ const float* pL[64];
    __shared__ const float* pR[64];
    __shared__ int tok[64];
    __shared__ __align__(16) short sXa[4 * 64 * 8];
    __shared__ __align__(16) short sXb[4 * 64 * 8];
    __shared__ __align__(16) short sXc[4 * 64 * 8];
    int count = *cnt;
    int m_base = task_off + (int)blockIdx.x * 64;
    if (m_base >= count) return;
    int tid = threadIdx.x;
    if (tid < 64) {
        int mg = m_base + tid;
        if (mg < count) {
            Task t = tasks[mg];
            pL[tid] = node_ptr(A.inp, A.arena, t.b, t.el);
            pR[tid] = node_ptr(A.inp, A.arena, t.b, t.er);
            tok[tid] = 1;
        } else { pL[tid] = A.inp; pR[tid] = A.inp; tok[tid] = 0; }
    }
    __syncthreads();
    const int n0 = blockIdx.y * 64;
    const int wid = tid >> 6, lane = tid & 63;
    const int wr = wid >> 1, wc = wid & 1;
    const int lrow = lane & 31, lhi = lane >> 5;
    const int colg = n0 + wc * 32 + lrow;
    const long wb = (long)colg * H2;
    const int srow = tid >> 2, smk = (tid & 3) * 8;   // smk/8 = seg = ch*2+hi
    const int wofs = (tid & 3) * 512 + srow * 8;      // write offset (shorts)
    const int rrow = wr * 32 + lrow;                  // fragment A-row

    const float* myL = pL[srow];
    const float* myR = pR[srow];

    f32x16 acc;
    #pragma unroll
    for (int r = 0; r < 16; ++r) acc[r] = 0.0f;

    float4 nv0 = *(const float4*)(myL + smk);
    float4 nv1 = *(const float4*)(myL + smk + 4);

    for (int kt = 0; kt < 32; ++kt) {
        const int k0 = kt * 32;
        float4 v0 = nv0, v1 = nv1;
        if (kt < 31) {
            const int k0n = (kt + 1) * 32;
            const float* nsrc = (k0n < HD ? myL + k0n + smk : myR + k0n - HD + smk);
            nv0 = *(const float4*)nsrc;
            nv1 = *(const float4*)(nsrc + 4);
        }
        {
            float f[8] = {v0.x, v0.y, v0.z, v0.w, v1.x, v1.y, v1.z, v1.w};
            bf16x8 ha, hb, hc;
            #pragma unroll
            for (int j = 0; j < 8; ++j) {
                short s1, s2, s3;
                split3(f[j], s1, s2, s3);
                ha[j] = s1; hb[j] = s2; hc[j] = s3;
            }
            *(bf16x8*)&sXa[wofs] = ha;
            *(bf16x8*)&sXb[wofs] = hb;
            *(bf16x8*)&sXc[wofs] = hc;
        }
        __syncthreads();
        #pragma unroll
        for (int ch = 0; ch < 2; ++ch) {
            const int ko = k0 + ch * 16 + lhi * 8;
            const int ao = (ch * 2 + lhi) * 512 + rrow * 8;
            bf16x8 a1 = *(const bf16x8*)&sXa[ao];
            bf16x8 a2 = *(const bf16x8*)&sXb[ao];
            bf16x8 a3 = *(const bf16x8*)&sXc[ao];
            bf16x8 b1 = *(const bf16x8*)&A.W1a[wb + ko];
            bf16x8 b2 = *(const bf16x8*)&A.W1b[wb + ko];
            bf16x8 b3 = *(const bf16x8*)&A.W1c[wb + ko];
            MFMA6(a1, a2, a3, b1, b2, b3, acc)
        }
        __syncthreads();
    }
    #pragma unroll
    for (int r = 0; r < 16; ++r) {
        int rl = wr * 32 + (r & 3) + 8 * (r >> 2) + 4 * lhi;
        if (!tok[rl]) continue;
        long vrow = (long)blockIdx.x * 64 + rl;
        float v = acc[r] + A.b1[colg];
        if (n0 < H2) {
            A.Vif[vrow * H2 + colg] = v;
        } else {
            int c2 = colg - H2;
            float rs = sigf(v);
            float xl = pL[rl][c2] * rs;
            float xr = pR[rl][c2] * rs;
            short s1, s2, s3;
            split3(xl, s1, s2, s3);
            long o1 = vrow * H2 + c2;
            A.X2a[o1] = s1; A.X2b[o1] = s2; A.X2c[o1] = s3;
            split3(xr, s1, s2, s3);
            long o2 = o1 + HD;
            A.X2a[o2] = s1; A.X2b[o2] = s2; A.X2c[o2] = s3;
        }
    }
}

// ================= G2 (R12/R15 verbatim) =================
__launch_bounds__(256, 6)
__global__ void k_g2(P A, const Task* __restrict__ tasks, const int* __restrict__ cnt, int task_off)
{
    __shared__ const float* pL[64];
    __shared__ const float* pR[64];
    __shared__ int dr[64];
    __shared__ int tok[64];
    int count = *cnt;
    int m_base = task_off + (int)blockIdx.x * 64;
    if (m_base >= count) return;
    int tid = threadIdx.x;
    if (tid < 64) {
        int mg = m_base + tid;
        if (mg < count) {
            Task t = tasks[mg];
            pL[tid] = node_ptr(A.inp, A.arena, t.b, t.el);
            pR[tid] = node_ptr(A.inp, A.arena, t.b, t.er);
            dr[tid] = t.b * TLEN + t.slot;
            tok[tid] = 1;
        } else { pL[tid] = A.inp; pR[tid] = A.inp; dr[tid] = 0; tok[tid] = 0; }
    }
    __syncthreads();
    const int n0 = blockIdx.y * 64;
    const int wid = tid >> 6, lane = tid & 63;
    const int wr = wid >> 1, wc = wid & 1;
    const int lrow = lane & 31, lhi = lane >> 5;
    const int colg = n0 + wc * 32 + lrow;
    const long wb = (long)colg * H2;
    const long arow = (long)((int)blockIdx.x * 64 + wr * 32 + lrow) * H2;
    const int klo = lhi * 8;

    f32x16 acc;
    #pragma unroll
    for (int r = 0; r < 16; ++r) acc[r] = 0.0f;

    #pragma unroll 4
    for (int kt = 0; kt < 32; ++kt) {
        #pragma unroll
        for (int ch = 0; ch < 2; ++ch) {
            const int ko = kt * 32 + ch * 16 + klo;
            bf16x8 a1 = *(const bf16x8*)&A.X2a[arow + ko];
            bf16x8 a2 = *(const bf16x8*)&A.X2b[arow + ko];
            bf16x8 a3 = *(const bf16x8*)&A.X2c[arow + ko];
            bf16x8 b1 = *(const bf16x8*)&A.W2a[wb + ko];
            bf16x8 b2 = *(const bf16x8*)&A.W2b[wb + ko];
            bf16x8 b3 = *(const bf16x8*)&A.W2c[wb + ko];
            MFMA6(a1, a2, a3, b1, b2, b3, acc)
        }
    }
    #pragma unroll
    for (int r = 0; r < 16; ++r) {
        int rl = wr * 32 + (r & 3) + 8 * (r >> 2) + 4 * lhi;
        if (!tok[rl]) continue;
        long vrow = (long)blockIdx.x * 64 + rl;
        float hh = acc[r] + A.b2[colg];
        float vi = A.Vif[vrow * H2 + colg];
        float vf = A.Vif[vrow * H2 + HD + colg];
        float l = pL[rl][colg];
        float rr = pR[rl][colg];
        float nh = (l + rr) * sigf(vf) + tanhf(hh) * sigf(vi);
        A.arena[(long)dr[rl] * HD + colg] = nh;
    }
}

// ================= init scoring: fp64, Wq1T coalesced (k_g3 ONLY — throughput regime) =================
__launch_bounds__(64)
__global__ void k_g3(P A)
{
    int tgl = blockIdx.x;
    if (tgl >= *A.cnt_init) return;
    Task t = A.itasks[tgl];
    int tid = threadIdx.x;
    __shared__ float nh[HD];
    __shared__ double part[64];
    const float* src = &A.arena[((long)t.b * TLEN + t.slot) * HD];
    for (int c = tid; c < HD; c += 64) nh[c] = src[c];
    __syncthreads();
    double p = 0.0;
    if (tid < HQ) {
        const float* wt = A.Wq1T;
        double s0 = 0.0, s1 = 0.0, s2 = 0.0, s3 = 0.0;
        for (int k = 0; k < HD; k += 4) {
            s0 += (double)wt[(k + 0) * HQ + tid] * (double)nh[k + 0];
            s1 += (double)wt[(k + 1) * HQ + tid] * (double)nh[k + 1];
            s2 += (double)wt[(k + 2) * HQ + tid] * (double)nh[k + 2];
            s3 += (double)wt[(k + 3) * HQ + tid] * (double)nh[k + 3];
        }
        double a = (double)A.bq1[tid] + s0 + s1 + s2 + s3;
        p = tanh(a) * (double)A.Wq2[tid];
    }
    part[tid] = p;
    __syncthreads();
    if (tid == 0) {
        double s = 0.0;
        for (int r = 0; r < HQ; ++r) s += part[r];
        s += (double)A.bq2[0];
        A.comp[t.b * TLEN + t.jl] = (float)s;
    }
}

// ================= select: 128 threads, row-major Wq1 (R15 verbatim — latency regime) =================
__launch_bounds__(128)
__global__ void k_select(P A, int iter, long off_i)
{
    int b = blockIdx.x, tid = threadIdx.x;
    __shared__ float nh[2][HD];
    __shared__ double part[2][64];
    __shared__ int sh[4];
    const Task* rtc = A.rtasks + (long)iter * MAXRT;
    Task* rtn = A.rtasks + (long)(iter + 1) * MAXRT;
    const int* ric = A.rti + (long)iter * (BATCH * 2);
    int* rin = A.rti + (long)(iter + 1) * (BATCH * 2);
    int* rc_nxt = A.rcnt + iter + 1;
    int len = A.length[b];
    if (iter == 62) {
        if (tid == 0 && len == TLEN) A.posval[b * TLEN + 0] = ARENA_BIT | A.cidx[b * TLEN + 0];
        return;
    }
    // 1) refresh comp: wave w handles task w
    {
        int w = tid >> 6, lane = tid & 63;
        int ti = ric[b * 2 + w];
        if (ti >= 0) {
            Task tk = rtc[ti];
            const float* src = &A.arena[((long)b * TLEN + tk.slot) * HD];
            for (int c = lane; c < HD; c += 64) nh[w][c] = src[c];
            double p = 0.0;
            if (lane < HQ) {
                const float* wr = &A.Wq1[(long)lane * HD];
                double s0 = 0.0, s1 = 0.0, s2 = 0.0, s3 = 0.0;
                for (int k = 0; k < HD; k += 4) {
                    s0 += (double)wr[k + 0] * (double)nh[w][k + 0];
                    s1 += (double)wr[k + 1] * (double)nh[w][k + 1];
                    s2 += (double)wr[k + 2] * (double)nh[w][k + 2];
                    s3 += (double)wr[k + 3] * (double)nh[w][k + 3];
                }
                double a = (double)A.bq1[lane] + s0 + s1 + s2 + s3;
                p = tanh(a) * (double)A.Wq2[lane];
            }
            part[w][lane] = p;
            if (lane == 0) {
                double s = 0.0;
                for (int r = 0; r < HQ; ++r) s += part[w][r];
                s += (double)A.bq2[0];
                A.comp[b * TLEN + tk.jl] = (float)s;
            }
        }
    }
    __syncthreads();
    // 2) argmax + mask
    int L1 = 63 - iter;
    if (tid == 0) {
        float best = -INFINITY; int bj = 0;
        for (int j = 0; j < L1; ++j) {
            float v = (iter + 1 + j < len) ? A.comp[b * TLEN + j] : -3.402823466e38f;
            if (v > best) { best = v; bj = j; }
        }
        sh[0] = bj;
    }
    __syncthreads();
    int bj = sh[0];
    if (tid < L1) A.out[off_i + (long)b * L1 + tid] = (tid == bj) ? 1.0f : 0.0f;
    bool active = (iter + 1) < len;
    if (active) {
        int vcnt = len - iter - 2;
        if (tid == 0) {
            sh[1] = A.cidx[b * TLEN + bj];
            sh[2] = (bj < vcnt) ? A.cidx[b * TLEN + bj + 1] : -1;
        }
        __syncthreads();
        int sM = sh[1], sOld = sh[2];
        int newL = 63 - iter;
        int pv = 0;  bool dp = (tid >= bj + 1 && tid <= newL - 1);
        if (dp) pv = A.posval[b * TLEN + tid + 1];
        float cv = 0; int civ = 0; bool dc = (tid >= bj + 1 && tid <= newL - 2);
        if (dc) { cv = A.comp[b * TLEN + tid + 1]; civ = A.cidx[b * TLEN + tid + 1]; }
        __syncthreads();
        if (dp) A.posval[b * TLEN + tid] = pv;
        if (dc) { A.comp[b * TLEN + tid] = cv; A.cidx[b * TLEN + tid] = civ; }
        if (tid == 0) A.posval[b * TLEN + bj] = ARENA_BIT | sM;
        __syncthreads();
        if (tid == 0) {
            for (int t = 0; t < 2; ++t) {
                int jn = bj - 1 + t;
                int r = -1;
                if (jn >= 0 && jn < vcnt) {
                    int slot = (t == 0) ? A.cidx[b * TLEN + jn] : sOld;
                    A.cidx[b * TLEN + jn] = slot;
                    r = atomicAdd(rc_nxt, 1);
                    Task tk; tk.b = b;
                    tk.el = A.posval[b * TLEN + jn];
                    tk.er = A.posval[b * TLEN + jn + 1];
                    tk.jl = jn; tk.slot = slot;
                    rtn[r] = tk;
                }
                rin[b * 2 + t] = r;
            }
        }
    } else {
        if (tid == 0) { rin[b * 2] = -1; rin[b * 2 + 1] = -1; }
    }
}

// ================= final output =================
__global__ void k_out(P A)
{
    int i = blockIdx.x * blockDim.x + threadIdx.x;
    if (i < BATCH * HD) {
        int b = i / HD, c = i % HD;
        const float* src = node_ptr(A.inp, A.arena, b, A.posval[b * TLEN + 0]);
        A.out[i] = src[c];
    }
}

// ================= launch =================
extern "C" void kernel_launch(void* const* d_in, const int* in_sizes, int n_in,
                              void* d_out, int out_size, void* d_ws, size_t ws_size,
                              hipStream_t stream)
{
    P a;
    a.inp = (const float*)d_in[0];
    a.length = (const int*)d_in[1];
    a.W1 = (const float*)d_in[2];
    a.b1 = (const float*)d_in[3];
    a.W2 = (const float*)d_in[4];
    a.b2 = (const float*)d_in[5];
    a.Wq1 = (const float*)d_in[6];
    a.bq1 = (const float*)d_in[7];
    a.Wq2 = (const float*)d_in[8];
    a.bq2 = (const float*)d_in[9];
    a.out = (float*)d_out;

    char* p = (char*)d_ws;
    auto alloc = [&](size_t bytes) { char* r = p; p += (bytes + 255) & ~(size_t)255; return r; };
    a.W1a = (short*)alloc((size_t)H3 * H2 * 2);
    a.W1b = (short*)alloc((size_t)H3 * H2 * 2);
    a.W1c = (short*)alloc((size_t)H3 * H2 * 2);
    a.W2a = (short*)alloc((size_t)HD * H2 * 2);
    a.W2b = (short*)alloc((size_t)HD * H2 * 2);
    a.W2c = (short*)alloc((size_t)HD * H2 * 2);
    a.Wq1T = (float*)alloc((size_t)HD * HQ * 4);
    a.Vif = (float*)alloc((size_t)CHUNK * H2 * 4);
    a.X2a = (short*)alloc((size_t)CHUNK * H2 * 2);
    a.X2b = (short*)alloc((size_t)CHUNK * H2 * 2);
    a.X2c = (short*)alloc((size_t)CHUNK * H2 * 2);
    a.arena = (float*)alloc((size_t)BATCH * TLEN * HD * 4);
    a.comp = (float*)alloc((size_t)BATCH * TLEN * 4);
    a.posval = (int*)alloc((size_t)BATCH * TLEN * 4);
    a.cidx = (int*)alloc((size_t)BATCH * TLEN * 4);
    a.itasks = (Task*)alloc((size_t)BATCH * (TLEN - 1) * sizeof(Task));
    a.rtasks = (Task*)alloc((size_t)64 * MAXRT * sizeof(Task));
    a.rti = (int*)alloc((size_t)64 * BATCH * 2 * 4);
    a.rcnt = (int*)alloc(64 * 4);
    a.cnt_init = (int*)alloc(256);

    k_prep<<<2048, 256, 0, stream>>>(a);
    k_init_tasks<<<BATCH, 64, 0, stream>>>(a.length, a.itasks, a.cnt_init);
    for (int c = 0; c < 8; ++c) {
        int off = c * CHUNK;
        k_g1<<<dim3(CHUNK / 64, 24), 256, 0, stream>>>(a, a.itasks, a.cnt_init, off);
        k_g2<<<dim3(CHUNK / 64, 8), 256, 0, stream>>>(a, a.itasks, a.cnt_init, off);
    }
    k_g3<<<BATCH * (TLEN - 1), 64, 0, stream>>>(a);
    long offi = (long)BATCH * HD;
    for (int i = 0; i < 63; ++i) {
        if (i >= 1) {
            const Task* rt = a.rtasks + (long)i * MAXRT;
            const int* rc = a.rcnt + i;
            k_g1<<<dim3(MAXRT / 64, 24), 256, 0, stream>>>(a, rt, rc, 0);
            k_g2<<<dim3(MAXRT / 64, 8), 256, 0, stream>>>(a, rt, rc, 0);
        }
        k_select<<<BATCH, 128, 0, stream>>>(a, i, offi);
        if (i < 62) offi += (long)BATCH * (63 - i);
    }
    k_out<<<(BATCH * HD + 255) / 256, 256, 0, stream>>>(a);
}

// Round 17
// 8528.011 us; speedup vs baseline: 1.2642x; 1.2122x over previous
//
#include <hip/hip_runtime.h>
#include <math.h>

#define BATCH 512
#define TLEN  64
#define HD    512
#define H2    1024
#define H3    1536
#define HQ    51
#define CHUNK 4096
#define ARENA_BIT 64
#define MAXRT 1024

typedef __attribute__((ext_vector_type(8))) short bf16x8;
typedef __attribute__((ext_vector_type(16))) float f32x16;

struct Task { int b, el, er, jl, slot; };

struct P {
    const float* inp; const int* length;
    const float* W1; const float* b1; const float* W2; const float* b2;
    const float* Wq1; const float* bq1; const float* Wq2; const float* bq2;
    float* out;
    short *W1a, *W1b, *W1c, *W2a, *W2b, *W2c;
    float* Wq1T;                  // [HD][HQ] transposed Wq1 — used ONLY by k_g3
    float* Vif;
    short *X2a, *X2b, *X2c;
    float* arena;
    float* comp; int* posval; int* cidx;
    Task* itasks; Task* rtasks;   // rtasks: 64 iteration slots x MAXRT
    int* rti;                     // 64 slots x BATCH*2
    int* rcnt;                    // 64
    int* cnt_init;
};

__device__ __forceinline__ float sigf(float x) { return 1.0f / (1.0f + expf(-x)); }

__device__ __forceinline__ unsigned short f2bf(float f) {
    unsigned u = __builtin_bit_cast(unsigned, f);
    u += 0x7fffu + ((u >> 16) & 1u);
    return (unsigned short)(u >> 16);
}
__device__ __forceinline__ float bf2f(unsigned short h) {
    unsigned u = ((unsigned)h) << 16;
    return __builtin_bit_cast(float, u);
}
__device__ __forceinline__ void split3(float f, short& a, short& b, short& c) {
    unsigned short h1 = f2bf(f);
    float r1 = f - bf2f(h1);
    unsigned short h2 = f2bf(r1);
    float r2 = r1 - bf2f(h2);
    unsigned short h3 = f2bf(r2);
    a = (short)h1; b = (short)h2; c = (short)h3;
}

__device__ __forceinline__ const float* node_ptr(const float* __restrict__ inp,
                                                 const float* __restrict__ arena,
                                                 int b, int enc)
{
    const float* base = (enc & ARENA_BIT) ? arena : inp;
    return base + ((long)b * TLEN + (enc & (ARENA_BIT - 1))) * HD;
}

#define MFMA6(a1,a2,a3,b1,b2,b3,acc) \
    acc = __builtin_amdgcn_mfma_f32_32x32x16_bf16(a1, b1, acc, 0, 0, 0); \
    acc = __builtin_amdgcn_mfma_f32_32x32x16_bf16(a1, b2, acc, 0, 0, 0); \
    acc = __builtin_amdgcn_mfma_f32_32x32x16_bf16(a2, b1, acc, 0, 0, 0); \
    acc = __builtin_amdgcn_mfma_f32_32x32x16_bf16(a1, b3, acc, 0, 0, 0); \
    acc = __builtin_amdgcn_mfma_f32_32x32x16_bf16(a2, b2, acc, 0, 0, 0); \
    acc = __builtin_amdgcn_mfma_f32_32x32x16_bf16(a3, b1, acc, 0, 0, 0);

// ================= prep / init tasks =================

__global__ void k_prep(P A)
{
    long tid = (long)blockIdx.x * blockDim.x + threadIdx.x;
    long nth = (long)gridDim.x * blockDim.x;
    for (long i = tid; i < (long)H3 * H2; i += nth) {
        short a, b, c; split3(A.W1[i], a, b, c);
        A.W1a[i] = a; A.W1b[i] = b; A.W1c[i] = c;
    }
    for (long i = tid; i < (long)HD * H2; i += nth) {
        short a, b, c; split3(A.W2[i], a, b, c);
        A.W2a[i] = a; A.W2b[i] = b; A.W2c[i] = c;
    }
    for (long i = tid; i < (long)HD * HQ; i += nth) {
        long k = i / HQ, q = i - k * HQ;
        A.Wq1T[i] = A.Wq1[q * HD + k];
    }
    for (long i = tid; i < BATCH * TLEN; i += nth) {
        int j = (int)(i % TLEN);
        A.posval[i] = j;
        A.cidx[i] = j;
    }
    for (long i = tid; i < BATCH * 2; i += nth) A.rti[i] = -1;   // iteration slot 0
    for (long i = tid; i < 64; i += nth) A.rcnt[i] = 0;
    if (tid == 0) *A.cnt_init = 0;
}

__global__ void k_init_tasks(const int* __restrict__ length, Task* __restrict__ tasks, int* __restrict__ cnt)
{
    int b = blockIdx.x, j = threadIdx.x;
    int len = length[b];
    if (j < len - 1) {
        int idx = atomicAdd(cnt, 1);
        Task t; t.b = b; t.el = j; t.er = j + 1; t.jl = j; t.slot = j;
        tasks[idx] = t;
    }
}

// ================= init G1 (R16 verbatim) =================
__launch_bounds__(256, 6)
__global__ void k_g1(P A, const Task* __restrict__ tasks, const int* __restrict__ cnt, int task_off)
{
    __shared__ const float* pL[64];
    __shared__ const float* pR[64];
    __shared__ int tok[64];
    __shared__ __align__(16) short sXa[4 * 64 * 8];
    __shared__ __align__(16) short sXb[4 * 64 * 8];
    __shared__ __align__(16) short sXc[4 * 64 * 8];
    int count = *cnt;
    int m_base = task_off + (int)blockIdx.x * 64;
    if (m_base >= count) return;
    int tid = threadIdx.x;
    if (tid < 64) {
        int mg = m_base + tid;
        if (mg < count) {
            Task t = tasks[mg];
            pL[tid] = node_ptr(A.inp, A.arena, t.b, t.el);
            pR[tid] = node_ptr(A.inp, A.arena, t.b, t.er);
            tok[tid] = 1;
        } else { pL[tid] = A.inp; pR[tid] = A.inp; tok[tid] = 0; }
    }
    __syncthreads();
    const int n0 = blockIdx.y * 64;
    const int wid = tid >> 6, lane = tid & 63;
    const int wr = wid >> 1, wc = wid & 1;
    const int lrow = lane & 31, lhi = lane >> 5;
    const int colg = n0 + wc * 32 + lrow;
    const long wb = (long)colg * H2;
    const int srow = tid >> 2, smk = (tid & 3) * 8;
    const int wofs = (tid & 3) * 512 + srow * 8;
    const int rrow = wr * 32 + lrow;

    const float* myL = pL[srow];
    const float* myR = pR[srow];

    f32x16 acc;
    #pragma unroll
    for (int r = 0; r < 16; ++r) acc[r] = 0.0f;

    float4 nv0 = *(const float4*)(myL + smk);
    float4 nv1 = *(const float4*)(myL + smk + 4);

    for (int kt = 0; kt < 32; ++kt) {
        const int k0 = kt * 32;
        float4 v0 = nv0, v1 = nv1;
        if (kt < 31) {
            const int k0n = (kt + 1) * 32;
            const float* nsrc = (k0n < HD ? myL + k0n + smk : myR + k0n - HD + smk);
            nv0 = *(const float4*)nsrc;
            nv1 = *(const float4*)(nsrc + 4);
        }
        {
            float f[8] = {v0.x, v0.y, v0.z, v0.w, v1.x, v1.y, v1.z, v1.w};
            bf16x8 ha, hb, hc;
            #pragma unroll
            for (int j = 0; j < 8; ++j) {
                short s1, s2, s3;
                split3(f[j], s1, s2, s3);
                ha[j] = s1; hb[j] = s2; hc[j] = s3;
            }
            *(bf16x8*)&sXa[wofs] = ha;
            *(bf16x8*)&sXb[wofs] = hb;
            *(bf16x8*)&sXc[wofs] = hc;
        }
        __syncthreads();
        #pragma unroll
        for (int ch = 0; ch < 2; ++ch) {
            const int ko = k0 + ch * 16 + lhi * 8;
            const int ao = (ch * 2 + lhi) * 512 + rrow * 8;
            bf16x8 a1 = *(const bf16x8*)&sXa[ao];
            bf16x8 a2 = *(const bf16x8*)&sXb[ao];
            bf16x8 a3 = *(const bf16x8*)&sXc[ao];
            bf16x8 b1 = *(const bf16x8*)&A.W1a[wb + ko];
            bf16x8 b2 = *(const bf16x8*)&A.W1b[wb + ko];
            bf16x8 b3 = *(const bf16x8*)&A.W1c[wb + ko];
            MFMA6(a1, a2, a3, b1, b2, b3, acc)
        }
        __syncthreads();
    }
    #pragma unroll
    for (int r = 0; r < 16; ++r) {
        int rl = wr * 32 + (r & 3) + 8 * (r >> 2) + 4 * lhi;
        if (!tok[rl]) continue;
        long vrow = (long)blockIdx.x * 64 + rl;
        float v = acc[r] + A.b1[colg];
        if (n0 < H2) {
            A.Vif[vrow * H2 + colg] = v;
        } else {
            int c2 = colg - H2;
            float rs = sigf(v);
            float xl = pL[rl][c2] * rs;
            float xr = pR[rl][c2] * rs;
            short s1, s2, s3;
            split3(xl, s1, s2, s3);
            long o1 = vrow * H2 + c2;
            A.X2a[o1] = s1; A.X2b[o1] = s2; A.X2c[o1] = s3;
            split3(xr, s1, s2, s3);
            long o2 = o1 + HD;
            A.X2a[o2] = s1; A.X2b[o2] = s2; A.X2c[o2] = s3;
        }
    }
}

// ================= init G2 (R16 verbatim) =================
__launch_bounds__(256, 6)
__global__ void k_g2(P A, const Task* __restrict__ tasks, const int* __restrict__ cnt, int task_off)
{
    __shared__ const float* pL[64];
    __shared__ const float* pR[64];
    __shared__ int dr[64];
    __shared__ int tok[64];
    int count = *cnt;
    int m_base = task_off + (int)blockIdx.x * 64;
    if (m_base >= count) return;
    int tid = threadIdx.x;
    if (tid < 64) {
        int mg = m_base + tid;
        if (mg < count) {
            Task t = tasks[mg];
            pL[tid] = node_ptr(A.inp, A.arena, t.b, t.el);
            pR[tid] = node_ptr(A.inp, A.arena, t.b, t.er);
            dr[tid] = t.b * TLEN + t.slot;
            tok[tid] = 1;
        } else { pL[tid] = A.inp; pR[tid] = A.inp; dr[tid] = 0; tok[tid] = 0; }
    }
    __syncthreads();
    const int n0 = blockIdx.y * 64;
    const int wid = tid >> 6, lane = tid & 63;
    const int wr = wid >> 1, wc = wid & 1;
    const int lrow = lane & 31, lhi = lane >> 5;
    const int colg = n0 + wc * 32 + lrow;
    const long wb = (long)colg * H2;
    const long arow = (long)((int)blockIdx.x * 64 + wr * 32 + lrow) * H2;
    const int klo = lhi * 8;

    f32x16 acc;
    #pragma unroll
    for (int r = 0; r < 16; ++r) acc[r] = 0.0f;

    #pragma unroll 4
    for (int kt = 0; kt < 32; ++kt) {
        #pragma unroll
        for (int ch = 0; ch < 2; ++ch) {
            const int ko = kt * 32 + ch * 16 + klo;
            bf16x8 a1 = *(const bf16x8*)&A.X2a[arow + ko];
            bf16x8 a2 = *(const bf16x8*)&A.X2b[arow + ko];
            bf16x8 a3 = *(const bf16x8*)&A.X2c[arow + ko];
            bf16x8 b1 = *(const bf16x8*)&A.W2a[wb + ko];
            bf16x8 b2 = *(const bf16x8*)&A.W2b[wb + ko];
            bf16x8 b3 = *(const bf16x8*)&A.W2c[wb + ko];
            MFMA6(a1, a2, a3, b1, b2, b3, acc)
        }
    }
    #pragma unroll
    for (int r = 0; r < 16; ++r) {
        int rl = wr * 32 + (r & 3) + 8 * (r >> 2) + 4 * lhi;
        if (!tok[rl]) continue;
        long vrow = (long)blockIdx.x * 64 + rl;
        float hh = acc[r] + A.b2[colg];
        float vi = A.Vif[vrow * H2 + colg];
        float vf = A.Vif[vrow * H2 + HD + colg];
        float l = pL[rl][colg];
        float rr = pR[rl][colg];
        float nh = (l + rr) * sigf(vf) + tanhf(hh) * sigf(vi);
        A.arena[(long)dr[rl] * HD + colg] = nh;
    }
}

// ================= refresh G1: 32-row x 128-thread tiles (bitwise-identical per-row math) =================
__launch_bounds__(128, 4)
__global__ void k_g1r(P A, const Task* __restrict__ tasks, const int* __restrict__ cnt)
{
    __shared__ const float* pL[32];
    __shared__ const float* pR[32];
    __shared__ int tok[32];
    __shared__ __align__(16) short sXa[4 * 32 * 8];
    __shared__ __align__(16) short sXb[4 * 32 * 8];
    __shared__ __align__(16) short sXc[4 * 32 * 8];
    int count = *cnt;
    int m_base = (int)blockIdx.x * 32;
    if (m_base >= count) return;
    int tid = threadIdx.x;
    if (tid < 32) {
        int mg = m_base + tid;
        if (mg < count) {
            Task t = tasks[mg];
            pL[tid] = node_ptr(A.inp, A.arena, t.b, t.el);
            pR[tid] = node_ptr(A.inp, A.arena, t.b, t.er);
            tok[tid] = 1;
        } else { pL[tid] = A.inp; pR[tid] = A.inp; tok[tid] = 0; }
    }
    __syncthreads();
    const int n0 = blockIdx.y * 64;
    const int wid = tid >> 6, lane = tid & 63;
    const int wc = wid;                              // 2 waves: col halves
    const int lrow = lane & 31, lhi = lane >> 5;
    const int colg = n0 + wc * 32 + lrow;
    const long wb = (long)colg * H2;
    const int srow = tid >> 2, smk = (tid & 3) * 8;  // 32 rows x 4 thr x 8 floats
    const int wofs = (tid & 3) * 256 + srow * 8;
    const int rrow = lrow;

    const float* myL = pL[srow];
    const float* myR = pR[srow];

    f32x16 acc;
    #pragma unroll
    for (int r = 0; r < 16; ++r) acc[r] = 0.0f;

    float4 nv0 = *(const float4*)(myL + smk);
    float4 nv1 = *(const float4*)(myL + smk + 4);

    for (int kt = 0; kt < 32; ++kt) {
        const int k0 = kt * 32;
        float4 v0 = nv0, v1 = nv1;
        if (kt < 31) {
            const int k0n = (kt + 1) * 32;
            const float* nsrc = (k0n < HD ? myL + k0n + smk : myR + k0n - HD + smk);
            nv0 = *(const float4*)nsrc;
            nv1 = *(const float4*)(nsrc + 4);
        }
        {
            float f[8] = {v0.x, v0.y, v0.z, v0.w, v1.x, v1.y, v1.z, v1.w};
            bf16x8 ha, hb, hc;
            #pragma unroll
            for (int j = 0; j < 8; ++j) {
                short s1, s2, s3;
                split3(f[j], s1, s2, s3);
                ha[j] = s1; hb[j] = s2; hc[j] = s3;
            }
            *(bf16x8*)&sXa[wofs] = ha;
            *(bf16x8*)&sXb[wofs] = hb;
            *(bf16x8*)&sXc[wofs] = hc;
        }
        __syncthreads();
        #pragma unroll
        for (int ch = 0; ch < 2; ++ch) {
            const int ko = k0 + ch * 16 + lhi * 8;
            const int ao = (ch * 2 + lhi) * 256 + rrow * 8;
            bf16x8 a1 = *(const bf16x8*)&sXa[ao];
            bf16x8 a2 = *(const bf16x8*)&sXb[ao];
            bf16x8 a3 = *(const bf16x8*)&sXc[ao];
            bf16x8 b1 = *(const bf16x8*)&A.W1a[wb + ko];
            bf16x8 b2 = *(const bf16x8*)&A.W1b[wb + ko];
            bf16x8 b3 = *(const bf16x8*)&A.W1c[wb + ko];
            MFMA6(a1, a2, a3, b1, b2, b3, acc)
        }
        __syncthreads();
    }
    #pragma unroll
    for (int r = 0; r < 16; ++r) {
        int rl = (r & 3) + 8 * (r >> 2) + 4 * lhi;
        if (!tok[rl]) continue;
        long vrow = (long)m_base + rl;
        float v = acc[r] + A.b1[colg];
        if (n0 < H2) {
            A.Vif[vrow * H2 + colg] = v;
        } else {
            int c2 = colg - H2;
            float rs = sigf(v);
            float xl = pL[rl][c2] * rs;
            float xr = pR[rl][c2] * rs;
            short s1, s2, s3;
            split3(xl, s1, s2, s3);
            long o1 = vrow * H2 + c2;
            A.X2a[o1] = s1; A.X2b[o1] = s2; A.X2c[o1] = s3;
            split3(xr, s1, s2, s3);
            long o2 = o1 + HD;
            A.X2a[o2] = s1; A.X2b[o2] = s2; A.X2c[o2] = s3;
        }
    }
}

// ================= refresh G2: 32-row x 128-thread tiles =================
__launch_bounds__(128, 4)
__global__ void k_g2r(P A, const Task* __restrict__ tasks, const int* __restrict__ cnt)
{
    __shared__ const float* pL[32];
    __shared__ const float* pR[32];
    __shared__ int dr[32];
    __shared__ int tok[32];
    int count = *cnt;
    int m_base = (int)blockIdx.x * 32;
    if (m_base >= count) return;
    int tid = threadIdx.x;
    if (tid < 32) {
        int mg = m_base + tid;
        if (mg < count) {
            Task t = tasks[mg];
            pL[tid] = node_ptr(A.inp, A.arena, t.b, t.el);
            pR[tid] = node_ptr(A.inp, A.arena, t.b, t.er);
            dr[tid] = t.b * TLEN + t.slot;
            tok[tid] = 1;
        } else { pL[tid] = A.inp; pR[tid] = A.inp; dr[tid] = 0; tok[tid] = 0; }
    }
    __syncthreads();
    const int n0 = blockIdx.y * 64;
    const int wid = tid >> 6, lane = tid & 63;
    const int wc = wid;
    const int lrow = lane & 31, lhi = lane >> 5;
    const int colg = n0 + wc * 32 + lrow;
    const long wb = (long)colg * H2;
    const long arow = (long)(m_base + lrow) * H2;
    const int klo = lhi * 8;

    f32x16 acc;
    #pragma unroll
    for (int r = 0; r < 16; ++r) acc[r] = 0.0f;

    #pragma unroll 4
    for (int kt = 0; kt < 32; ++kt) {
        #pragma unroll
        for (int ch = 0; ch < 2; ++ch) {
            const int ko = kt * 32 + ch * 16 + klo;
            bf16x8 a1 = *(const bf16x8*)&A.X2a[arow + ko];
            bf16x8 a2 = *(const bf16x8*)&A.X2b[arow + ko];
            bf16x8 a3 = *(const bf16x8*)&A.X2c[arow + ko];
            bf16x8 b1 = *(const bf16x8*)&A.W2a[wb + ko];
            bf16x8 b2 = *(const bf16x8*)&A.W2b[wb + ko];
            bf16x8 b3 = *(const bf16x8*)&A.W2c[wb + ko];
            MFMA6(a1, a2, a3, b1, b2, b3, acc)
        }
    }
    #pragma unroll
    for (int r = 0; r < 16; ++r) {
        int rl = (r & 3) + 8 * (r >> 2) + 4 * lhi;
        if (!tok[rl]) continue;
        long vrow = (long)m_base + rl;
        float hh = acc[r] + A.b2[colg];
        float vi = A.Vif[vrow * H2 + colg];
        float vf = A.Vif[vrow * H2 + HD + colg];
        float l = pL[rl][colg];
        float rr = pR[rl][colg];
        float nh = (l + rr) * sigf(vf) + tanhf(hh) * sigf(vi);
        A.arena[(long)dr[rl] * HD + colg] = nh;
    }
}

// ================= init scoring: fp64, Wq1T coalesced (R16 verbatim) =================
__launch_bounds__(64)
__global__ void k_g3(P A)
{
    int tgl = blockIdx.x;
    if (tgl >= *A.cnt_init) return;
    Task t = A.itasks[tgl];
    int tid = threadIdx.x;
    __shared__ float nh[HD];
    __shared__ double part[64];
    const float* src = &A.arena[((long)t.b * TLEN + t.slot) * HD];
    for (int c = tid; c < HD; c += 64) nh[c] = src[c];
    __syncthreads();
    double p = 0.0;
    if (tid < HQ) {
        const float* wt = A.Wq1T;
        double s0 = 0.0, s1 = 0.0, s2 = 0.0, s3 = 0.0;
        for (int k = 0; k < HD; k += 4) {
            s0 += (double)wt[(k + 0) * HQ + tid] * (double)nh[k + 0];
            s1 += (double)wt[(k + 1) * HQ + tid] * (double)nh[k + 1];
            s2 += (double)wt[(k + 2) * HQ + tid] * (double)nh[k + 2];
            s3 += (double)wt[(k + 3) * HQ + tid] * (double)nh[k + 3];
        }
        double a = (double)A.bq1[tid] + s0 + s1 + s2 + s3;
        p = tanh(a) * (double)A.Wq2[tid];
    }
    part[tid] = p;
    __syncthreads();
    if (tid == 0) {
        double s = 0.0;
        for (int r = 0; r < HQ; ++r) s += part[r];
        s += (double)A.bq2[0];
        A.comp[t.b * TLEN + t.jl] = (float)s;
    }
}

// ================= select: 128 threads, row-major Wq1 (R16 verbatim) =================
__launch_bounds__(128)
__global__ void k_select(P A, int iter, long off_i)
{
    int b = blockIdx.x, tid = threadIdx.x;
    __shared__ float nh[2][HD];
    __shared__ double part[2][64];
    __shared__ int sh[4];
    const Task* rtc = A.rtasks + (long)iter * MAXRT;
    Task* rtn = A.rtasks + (long)(iter + 1) * MAXRT;
    const int* ric = A.rti + (long)iter * (BATCH * 2);
    int* rin = A.rti + (long)(iter + 1) * (BATCH * 2);
    int* rc_nxt = A.rcnt + iter + 1;
    int len = A.length[b];
    if (iter == 62) {
        if (tid == 0 && len == TLEN) A.posval[b * TLEN + 0] = ARENA_BIT | A.cidx[b * TLEN + 0];
        return;
    }
    {
        int w = tid >> 6, lane = tid & 63;
        int ti = ric[b * 2 + w];
        if (ti >= 0) {
            Task tk = rtc[ti];
            const float* src = &A.arena[((long)b * TLEN + tk.slot) * HD];
            for (int c = lane; c < HD; c += 64) nh[w][c] = src[c];
            double p = 0.0;
            if (lane < HQ) {
                const float* wr = &A.Wq1[(long)lane * HD];
                double s0 = 0.0, s1 = 0.0, s2 = 0.0, s3 = 0.0;
                for (int k = 0; k < HD; k += 4) {
                    s0 += (double)wr[k + 0] * (double)nh[w][k + 0];
                    s1 += (double)wr[k + 1] * (double)nh[w][k + 1];
                    s2 += (double)wr[k + 2] * (double)nh[w][k + 2];
                    s3 += (double)wr[k + 3] * (double)nh[w][k + 3];
                }
                double a = (double)A.bq1[lane] + s0 + s1 + s2 + s3;
                p = tanh(a) * (double)A.Wq2[lane];
            }
            part[w][lane] = p;
            if (lane == 0) {
                double s = 0.0;
                for (int r = 0; r < HQ; ++r) s += part[w][r];
                s += (double)A.bq2[0];
                A.comp[b * TLEN + tk.jl] = (float)s;
            }
        }
    }
    __syncthreads();
    int L1 = 63 - iter;
    if (tid == 0) {
        float best = -INFINITY; int bj = 0;
        for (int j = 0; j < L1; ++j) {
            float v = (iter + 1 + j < len) ? A.comp[b * TLEN + j] : -3.402823466e38f;
            if (v > best) { best = v; bj = j; }
        }
        sh[0] = bj;
    }
    __syncthreads();
    int bj = sh[0];
    if (tid < L1) A.out[off_i + (long)b * L1 + tid] = (tid == bj) ? 1.0f : 0.0f;
    bool active = (iter + 1) < len;
    if (active) {
        int vcnt = len - iter - 2;
        if (tid == 0) {
            sh[1] = A.cidx[b * TLEN + bj];
            sh[2] = (bj < vcnt) ? A.cidx[b * TLEN + bj + 1] : -1;
        }
        __syncthreads();
        int sM = sh[1], sOld = sh[2];
        int newL = 63 - iter;
        int pv = 0;  bool dp = (tid >= bj + 1 && tid <= newL - 1);
        if (dp) pv = A.posval[b * TLEN + tid + 1];
        float cv = 0; int civ = 0; bool dc = (tid >= bj + 1 && tid <= newL - 2);
        if (dc) { cv = A.comp[b * TLEN + tid + 1]; civ = A.cidx[b * TLEN + tid + 1]; }
        __syncthreads();
        if (dp) A.posval[b * TLEN + tid] = pv;
        if (dc) { A.comp[b * TLEN + tid] = cv; A.cidx[b * TLEN + tid] = civ; }
        if (tid == 0) A.posval[b * TLEN + bj] = ARENA_BIT | sM;
        __syncthreads();
        if (tid == 0) {
            for (int t = 0; t < 2; ++t) {
                int jn = bj - 1 + t;
                int r = -1;
                if (jn >= 0 && jn < vcnt) {
                    int slot = (t == 0) ? A.cidx[b * TLEN + jn] : sOld;
                    A.cidx[b * TLEN + jn] = slot;
                    r = atomicAdd(rc_nxt, 1);
                    Task tk; tk.b = b;
                    tk.el = A.posval[b * TLEN + jn];
                    tk.er = A.posval[b * TLEN + jn + 1];
                    tk.jl = jn; tk.slot = slot;
                    rtn[r] = tk;
                }
                rin[b * 2 + t] = r;
            }
        }
    } else {
        if (tid == 0) { rin[b * 2] = -1; rin[b * 2 + 1] = -1; }
    }
}

// ================= final output =================
__global__ void k_out(P A)
{
    int i = blockIdx.x * blockDim.x + threadIdx.x;
    if (i < BATCH * HD) {
        int b = i / HD, c = i % HD;
        const float* src = node_ptr(A.inp, A.arena, b, A.posval[b * TLEN + 0]);
        A.out[i] = src[c];
    }
}

// ================= launch =================
extern "C" void kernel_launch(void* const* d_in, const int* in_sizes, int n_in,
                              void* d_out, int out_size, void* d_ws, size_t ws_size,
                              hipStream_t stream)
{
    P a;
    a.inp = (const float*)d_in[0];
    a.length = (const int*)d_in[1];
    a.W1 = (const float*)d_in[2];
    a.b1 = (const float*)d_in[3];
    a.W2 = (const float*)d_in[4];
    a.b2 = (const float*)d_in[5];
    a.Wq1 = (const float*)d_in[6];
    a.bq1 = (const float*)d_in[7];
    a.Wq2 = (const float*)d_in[8];
    a.bq2 = (const float*)d_in[9];
    a.out = (float*)d_out;

    char* p = (char*)d_ws;
    auto alloc = [&](size_t bytes) { char* r = p; p += (bytes + 255) & ~(size_t)255; return r; };
    a.W1a = (short*)alloc((size_t)H3 * H2 * 2);
    a.W1b = (short*)alloc((size_t)H3 * H2 * 2);
    a.W1c = (short*)alloc((size_t)H3 * H2 * 2);
    a.W2a = (short*)alloc((size_t)HD * H2 * 2);
    a.W2b = (short*)alloc((size_t)HD * H2 * 2);
    a.W2c = (short*)alloc((size_t)HD * H2 * 2);
    a.Wq1T = (float*)alloc((size_t)HD * HQ * 4);
    a.Vif = (float*)alloc((size_t)CHUNK * H2 * 4);
    a.X2a = (short*)alloc((size_t)CHUNK * H2 * 2);
    a.X2b = (short*)alloc((size_t)CHUNK * H2 * 2);
    a.X2c = (short*)alloc((size_t)CHUNK * H2 * 2);
    a.arena = (float*)alloc((size_t)BATCH * TLEN * HD * 4);
    a.comp = (float*)alloc((size_t)BATCH * TLEN * 4);
    a.posval = (int*)alloc((size_t)BATCH * TLEN * 4);
    a.cidx = (int*)alloc((size_t)BATCH * TLEN * 4);
    a.itasks = (Task*)alloc((size_t)BATCH * (TLEN - 1) * sizeof(Task));
    a.rtasks = (Task*)alloc((size_t)64 * MAXRT * sizeof(Task));
    a.rti = (int*)alloc((size_t)64 * BATCH * 2 * 4);
    a.rcnt = (int*)alloc(64 * 4);
    a.cnt_init = (int*)alloc(256);

    k_prep<<<2048, 256, 0, stream>>>(a);
    k_init_tasks<<<BATCH, 64, 0, stream>>>(a.length, a.itasks, a.cnt_init);
    for (int c = 0; c < 8; ++c) {
        int off = c * CHUNK;
        k_g1<<<dim3(CHUNK / 64, 24), 256, 0, stream>>>(a, a.itasks, a.cnt_init, off);
        k_g2<<<dim3(CHUNK / 64, 8), 256, 0, stream>>>(a, a.itasks, a.cnt_init, off);
    }
    k_g3<<<BATCH * (TLEN - 1), 64, 0, stream>>>(a);
    long offi = (long)BATCH * HD;
    for (int i = 0; i < 63; ++i) {
        if (i >= 1) {
            const Task* rt = a.rtasks + (long)i * MAXRT;
            const int* rc = a.rcnt + i;
            k_g1r<<<dim3(MAXRT / 32, 24), 128, 0, stream>>>(a, rt, rc);
            k_g2r<<<dim3(MAXRT / 32, 8), 128, 0, stream>>>(a, rt, rc);
        }
        k_select<<<BATCH, 128, 0, stream>>>(a, i, offi);
        if (i < 62) offi += (long)BATCH * (63 - i);
    }
    k_out<<<(BATCH * HD + 255) / 256, 256, 0, stream>>>(a);
}